// Round 2
// baseline (455.313 us; speedup 1.0000x reference)
//
#include <hip/hip_runtime.h>
#include <stdint.h>

// Problem constants
#define B_   128
#define C_   500
#define H_   16
#define P_   256      // 16*16 pixels per image
#define D_   192
#define C1O  300
#define H1   34
#define P1   (H1*H1)  // 1156
#define C2O  100
#define H2   36
#define P2   (H2*H2)  // 1296
#define C3O  3
#define H3   38
#define P3   (H3*H3)  // 1444
#define CROP 3
#define OW_  32
#define KTOP 30

__device__ __forceinline__ float sgnf(float v){ return (v > 0.f) ? 1.f : ((v < 0.f) ? -1.f : 0.f); }

// tap-validity pattern for a position in a length-36 conv output coming from a
// length-34 input (k=3, stride=1 transposed conv).
__device__ __forceinline__ int pat36(int i){
  if (i == 0) return 0;       // {0}
  if (i == 1) return 1;       // {0,1}
  if (i <= 33) return 2;      // {0,1,2}
  if (i == 34) return 3;      // {1,2}
  return 4;                   // {2}
}

// =====================================================================
// k_setup: block-specialized.
//   blocks 0..37   : base3 row oh=blockIdx (recompute S/tab in LDS, block 0
//                    also publishes tab to global for k_u2f)
//   block  38      : l1 + thr
//   blocks 39..102 : zero d1+d2 region (313856 B, float4 grid-stride)
// =====================================================================
__global__ void k_setup(const float* __restrict__ phi, const float* __restrict__ jumpp,
                        const float* __restrict__ w2, const float* __restrict__ b1,
                        const float* __restrict__ b2, const float* __restrict__ w3,
                        const float* __restrict__ b3,
                        float* __restrict__ l1, float* __restrict__ thr,
                        float* __restrict__ tab, float* __restrict__ base3,
                        float4* __restrict__ zero_region){
  const int blk = blockIdx.x;
  const int t = threadIdx.x;   // 256

  if (blk >= 39){              // ---- zeroing blocks ----
    const int idx0 = (blk - 39) * 256 + t;
    const int nvec = (B_ * P1 + B_ * P2) / 16;   // 19616
    float4 z = make_float4(0.f, 0.f, 0.f, 0.f);
    for (int i = idx0; i < nvec; i += 64 * 256) zero_region[i] = z;
    return;
  }

  if (blk == 38){              // ---- l1 / thr ----
    float J = jumpp[0];
    for (int c = t; c < C_; c += 256){
      float s = 0.f;
      for (int d = 0; d < D_; ++d) s += fabsf(phi[d * C_ + c]);
      s += 1e-12f;
      l1[c] = s;
      thr[c] = J * s;
    }
    return;
  }

  // ---- base3 row blk (0..37). Recompute S (900) and tab (2500) in LDS ----
  __shared__ float S_sh[900];
  __shared__ float tab_sh[2500];

  float acc[4] = {0, 0, 0, 0};
  for (int c = 0; c < C1O; ++c){
    float a1 = fmaxf(b1[c], 0.f);
    const float* w = w2 + c * 900;
#pragma unroll
    for (int r = 0; r < 4; ++r){
      int idx = t + r * 256;
      if (idx < 900) acc[r] += w[idx] * a1;
    }
  }
#pragma unroll
  for (int r = 0; r < 4; ++r){
    int idx = t + r * 256;
    if (idx < 900) S_sh[idx] = acc[r];
  }
  __syncthreads();

  const int lo[5] = {0,0,0,1,2}, hi[5] = {0,1,2,2,2};
  for (int e = t; e < 2500; e += 256){
    int o = e / 25, r = e % 25, pr = r / 5, pc = r % 5;
    float s = b2[o];
    for (int kh = lo[pr]; kh <= hi[pr]; ++kh)
      for (int kw = lo[pc]; kw <= hi[pc]; ++kw) s += S_sh[o * 9 + kh * 3 + kw];
    tab_sh[e] = s;
    if (blk == 0) tab[e] = s;       // publish (pre-relu), used by k_u2f
  }
  __syncthreads();

  if (t < 114){
    int o = t % 3, ow = t / 3;      // ow in [0,38)
    int oh = blk;
    float acc3 = b3[o];
    for (int kh = 0; kh < 3; ++kh){
      int ih = oh - kh; if (ih < 0 || ih >= H2) continue;
      int prr = pat36(ih) * 5;
      for (int kw = 0; kw < 3; ++kw){
        int iw = ow - kw; if (iw < 0 || iw >= H2) continue;
        int pp = prr + pat36(iw);
        const float* wp = w3 + o * 9 + kh * 3 + kw;
        for (int c2 = 0; c2 < C2O; ++c2)
          acc3 += wp[c2 * 27] * fmaxf(tab_sh[c2 * 25 + pp], 0.f);
      }
    }
    base3[o * P3 + oh * H3 + ow] = acc3;
  }
}

// =====================================================================
// k_zq: one pass over x with float4 loads; per-pixel hot flag. Cold path
// (only if a pixel in the tile is flagged): exact top-30 + quantization.
// =====================================================================
__global__ void k_zq(const float* __restrict__ x, const float* __restrict__ l1,
                     const float* __restrict__ thr, const float* __restrict__ jumpp,
                     signed char* __restrict__ zq, unsigned char* __restrict__ d0){
  const int b = blockIdx.x >> 2;
  const int tile = (blockIdx.x & 3) * 64;
  const int t = threadIdx.x;            // 256
  const int q = t & 15, cg = t >> 4;    // pixel-quad, channel-group

  __shared__ unsigned char um[256];
  __shared__ unsigned char pixf[64];
  __shared__ int s_any;
  if (t == 0) s_any = 0;

  unsigned m = 0;
  const int pbase = tile + 4 * q;
  for (int c = cg; c < C_; c += 16){
    float tc = thr[c];
    const float4 v = *(const float4*)(x + ((size_t)(b * C_ + c)) * P_ + pbase);
    if (fabsf(v.x) >= tc) m |= 1u;
    if (fabsf(v.y) >= tc) m |= 2u;
    if (fabsf(v.z) >= tc) m |= 4u;
    if (fabsf(v.w) >= tc) m |= 8u;
  }
  um[t] = (unsigned char)m;
  __syncthreads();
  if (t < 16){
    unsigned mm = 0;
#pragma unroll
    for (int g = 0; g < 16; ++g) mm |= um[g * 16 + t];
#pragma unroll
    for (int j = 0; j < 4; ++j){
      unsigned char f = (unsigned char)((mm >> j) & 1u);
      pixf[4 * t + j] = f;
      d0[b * P_ + tile + 4 * t + j] = f;
    }
    if (mm) s_any = 1;                  // benign race, all write 1
  }
  __syncthreads();
  if (!s_any) return;

  // ---- cold path: exact top-30 (jax ties: lower index wins) + quant ----
  __shared__ float sx[C_];
  __shared__ unsigned char rm[C_];
  __shared__ unsigned long long red[4];
  __shared__ int sel[KTOP];
  float J = jumpp[0];
  for (int pp = 0; pp < 64; ++pp){
    if (!pixf[pp]) continue;
    int px = tile + pp;
    for (int c = t; c < C_; c += 256){ sx[c] = x[(b * C_ + c) * P_ + px]; rm[c] = 0; }
    __syncthreads();
    for (int it = 0; it < KTOP; ++it){
      unsigned long long best = 0ULL;
      for (int c = t; c < C_; c += 256){
        if (!rm[c]){
          unsigned long long key =
            ((unsigned long long)__float_as_uint(fabsf(sx[c])) << 32) |
            (unsigned int)(C_ - 1 - c);
          if (key > best) best = key;
        }
      }
      for (int off = 32; off; off >>= 1){
        unsigned long long o2 = __shfl_down(best, off);
        if (o2 > best) best = o2;
      }
      if ((t & 63) == 0) red[t >> 6] = best;
      __syncthreads();
      if (t == 0){
        unsigned long long mx = red[0];
        for (int wv = 1; wv < 4; ++wv) if (red[wv] > mx) mx = red[wv];
        int idx = C_ - 1 - (int)(mx & 0xffffffffULL);
        sel[it] = idx;
        rm[idx] = 1;
      }
      __syncthreads();
    }
    for (int c = t; c < C_; c += 256) zq[(b * C_ + c) * P_ + px] = 0;
    __syncthreads();
    if (t < KTOP){
      int c = sel[t];
      float z = sx[c];
      float r = z / l1[c];
      float qv = 0.5f * (sgnf(r - J) + sgnf(r + J));  // {-1,-0.5,0,0.5,1}
      int code = (int)(2.f * qv);                     // {-2,-1,0,1,2}
      if (code) zq[(b * C_ + c) * P_ + px] = (signed char)code;
    }
    __syncthreads();
  }
}

// =====================================================================
// k_u1f: fused scan1+u1. 64 threads/block = 1 wave; lane checks one
// level-1 pixel; ballot; compute u1 per dirty pixel with the whole wave.
// =====================================================================
__global__ void k_u1f(const signed char* __restrict__ zq, const float* __restrict__ l1,
                      const float* __restrict__ w1, const float* __restrict__ b1,
                      const unsigned char* __restrict__ d0,
                      unsigned char* __restrict__ d1, float* __restrict__ u1, int have){
  const int lane = threadIdx.x;   // 64
  const int pix0 = blockIdx.x * 64;
  const int tid = pix0 + lane;

  int b = tid / P1, p1 = tid - b * P1;
  int ih = p1 / H1, iw = p1 - ih * H1;
  int h0 = max(0, (ih - 2) >> 1), h1v = min(H_ - 1, ih >> 1);
  int w0 = max(0, (iw - 2) >> 1), w1v = min(H_ - 1, iw >> 1);
  int any = 0;
  for (int h = h0; h <= h1v; ++h)
    for (int w = w0; w <= w1v; ++w)
      any |= d0[b * P_ + h * H_ + w];
  unsigned long long mask = __ballot(any != 0);
  if (!mask) return;
  if (any) d1[tid] = 1;

  while (mask){
    int pp = __ffsll((long long)mask) - 1;
    mask &= mask - 1;
    int pix = pix0 + pp;
    int bb = pix / P1, pq = pix - bb * P1;
    int oih = pq / H1, oiw = pq - oih * H1;
    float acc[5] = {0,0,0,0,0};
    int hh0 = max(0, (oih - 2) >> 1), hh1 = min(H_ - 1, oih >> 1);
    int ww0 = max(0, (oiw - 2) >> 1), ww1 = min(H_ - 1, oiw >> 1);
    for (int h = hh0; h <= hh1; ++h)
      for (int w = ww0; w <= ww1; ++w){
        if (!d0[bb * P_ + h * H_ + w]) continue;
        int kh = oih - 2 * h, kw = oiw - 2 * w;
        const signed char* zp = zq + (size_t)(bb * C_) * P_ + h * H_ + w;
        for (int c = 0; c < C_; ++c){
          int code = zp[(size_t)c * P_];
          if (!code) continue;
          float val = 0.5f * (float)code * l1[c];
          const float* wp = w1 + (size_t)(c * C1O) * 16 + kh * 4 + kw;
#pragma unroll
          for (int j = 0; j < 5; ++j){
            int c1 = j * 64 + lane;
            if (c1 < C1O) acc[j] += wp[(size_t)c1 * 16] * val;
          }
        }
      }
    if (have){
#pragma unroll
      for (int j = 0; j < 5; ++j){
        int c1 = j * 64 + lane;
        if (c1 < C1O){
          float bb1 = b1[c1];
          u1[(size_t)(bb * C1O + c1) * P1 + pq] = fmaxf(bb1 + acc[j], 0.f) - fmaxf(bb1, 0.f);
        }
      }
    }
  }
}

// =====================================================================
// k_u2f: fused scan2+u2, same structure.
// =====================================================================
__global__ void k_u2f(const float* __restrict__ u1, const float* __restrict__ w2,
                      const float* __restrict__ tab, const unsigned char* __restrict__ d1,
                      unsigned char* __restrict__ d2, float* __restrict__ u2, int have){
  const int lane = threadIdx.x;   // 64
  const int pix0 = blockIdx.x * 64;
  const int tid = pix0 + lane;

  int b = tid / P2, p2 = tid - b * P2;
  int oh = p2 / H2, ow = p2 - oh * H2;
  int any = 0;
  for (int kh = 0; kh < 3; ++kh){
    int ih = oh - kh; if (ih < 0 || ih >= H1) continue;
    for (int kw = 0; kw < 3; ++kw){
      int iw = ow - kw; if (iw < 0 || iw >= H1) continue;
      any |= d1[b * P1 + ih * H1 + iw];
    }
  }
  unsigned long long mask = __ballot(any != 0);
  if (!mask) return;
  if (any) d2[tid] = 1;

  while (mask){
    int pp = __ffsll((long long)mask) - 1;
    mask &= mask - 1;
    int pix = pix0 + pp;
    int bb = pix / P2, pq = pix - bb * P2;
    int ooh = pq / H2, oow = pq - ooh * H2;
    float acc[2] = {0,0};
    for (int kh = 0; kh < 3; ++kh){
      int ih = ooh - kh; if (ih < 0 || ih >= H1) continue;
      for (int kw = 0; kw < 3; ++kw){
        int iw = oow - kw; if (iw < 0 || iw >= H1) continue;
        if (!d1[bb * P1 + ih * H1 + iw]) continue;
        const float* up = u1 + (size_t)(bb * C1O) * P1 + ih * H1 + iw;
        const float* wb = w2 + kh * 3 + kw;
        for (int c1 = 0; c1 < C1O; ++c1){
          float uv = up[(size_t)c1 * P1];
          if (uv == 0.f) continue;
          const float* wp = wb + (size_t)(c1 * C2O) * 9;
#pragma unroll
          for (int j = 0; j < 2; ++j){
            int c2 = j * 64 + lane;
            if (c2 < C2O) acc[j] += wp[(size_t)c2 * 9] * uv;
          }
        }
      }
    }
    if (have){
      int pr = pat36(ooh) * 5 + pat36(oow);
#pragma unroll
      for (int j = 0; j < 2; ++j){
        int c2 = j * 64 + lane;
        if (c2 < C2O){
          float bs = tab[c2 * 25 + pr];
          u2[(size_t)(bb * C2O + c2) * P2 + pq] = fmaxf(bs + acc[j], 0.f) - fmaxf(bs, 0.f);
        }
      }
    }
  }
}

// ----------------------------------------------------------- final output
__global__ void k_out(const float* __restrict__ base3, const unsigned char* __restrict__ d2,
                      const float* __restrict__ u2, const float* __restrict__ w3,
                      float* __restrict__ out){
  int tid = blockIdx.x * blockDim.x + threadIdx.x;
  if (tid >= B_ * OW_ * OW_) return;
  int b = tid >> 10;
  int rc = tid & 1023;
  int r = rc >> 5, cc = rc & 31;
  int oh = r + CROP, ow = cc + CROP;   // all 9 taps in-bounds
  int any = 0;
#pragma unroll
  for (int kh = 0; kh < 3; ++kh)
#pragma unroll
    for (int kw = 0; kw < 3; ++kw)
      any |= d2[b * P2 + (oh - kh) * H2 + (ow - kw)];
  if (!any){
#pragma unroll
    for (int o = 0; o < 3; ++o)
      out[((b * 3 + o) * OW_ + r) * OW_ + cc] = fmaxf(base3[o * P3 + oh * H3 + ow], 0.f);
    return;
  }
  float acc[3];
#pragma unroll
  for (int o = 0; o < 3; ++o) acc[o] = base3[o * P3 + oh * H3 + ow];
  for (int kh = 0; kh < 3; ++kh){
    int ih = oh - kh;
    for (int kw = 0; kw < 3; ++kw){
      int iw = ow - kw;
      if (!d2[b * P2 + ih * H2 + iw]) continue;
      const float* up = u2 + (size_t)(b * C2O) * P2 + ih * H2 + iw;
      const float* wb = w3 + kh * 3 + kw;
      for (int c2 = 0; c2 < C2O; ++c2){
        float uv = up[(size_t)c2 * P2];
        if (uv == 0.f) continue;
        const float* wp = wb + c2 * 27;
#pragma unroll
        for (int o = 0; o < 3; ++o) acc[o] += wp[o * 9] * uv;
      }
    }
  }
#pragma unroll
  for (int o = 0; o < 3; ++o)
    out[((b * 3 + o) * OW_ + r) * OW_ + cc] = fmaxf(acc[o], 0.f);
}

extern "C" void kernel_launch(void* const* d_in, const int* in_sizes, int n_in,
                              void* d_out, int out_size, void* d_ws, size_t ws_size,
                              hipStream_t stream){
  const float* x   = (const float*)d_in[0];
  const float* phi = (const float*)d_in[1];
  const float* jmp = (const float*)d_in[2];
  const float* w1  = (const float*)d_in[3];
  const float* b1  = (const float*)d_in[4];
  const float* w2  = (const float*)d_in[5];
  const float* b2  = (const float*)d_in[6];
  const float* w3  = (const float*)d_in[7];
  const float* b3  = (const float*)d_in[8];
  float* out = (float*)d_out;
  char* ws = (char*)d_ws;

  // workspace layout (bytes, 16B-aligned)
  constexpr size_t OFF_L1  = 0;                                  // 500 f32
  constexpr size_t OFF_THR = OFF_L1  + 2048;                     // 500 f32
  constexpr size_t OFF_TAB = OFF_THR + 2048;                     // 2500 f32
  constexpr size_t OFF_B3  = OFF_TAB + 10240;                    // 4332 f32
  constexpr size_t OFF_D0  = OFF_B3  + 17344;                    // 32768 u8
  constexpr size_t OFF_D1  = OFF_D0  + (size_t)B_ * P_;          // u8
  constexpr size_t OFF_D2  = OFF_D1  + (size_t)B_ * P1;          // u8
  constexpr size_t OFF_ZQ  = OFF_D2  + (size_t)B_ * P2;          // i8 codes
  constexpr size_t OFF_U1  = OFF_ZQ  + (size_t)B_ * C_ * P_;
  constexpr size_t OFF_U2  = OFF_U1  + (size_t)B_ * C1O * P1 * 4;
  constexpr size_t TOTAL   = OFF_U2  + (size_t)B_ * C2O * P2 * 4;

  float* l1p  = (float*)(ws + OFF_L1);
  float* thrp = (float*)(ws + OFF_THR);
  float* tabp = (float*)(ws + OFF_TAB);
  float* b3p  = (float*)(ws + OFF_B3);
  unsigned char* d0p = (unsigned char*)(ws + OFF_D0);
  unsigned char* d1p = (unsigned char*)(ws + OFF_D1);
  unsigned char* d2p = (unsigned char*)(ws + OFF_D2);
  signed char* zqp = (signed char*)(ws + OFF_ZQ);
  float* u1p = (float*)(ws + OFF_U1);
  float* u2p = (float*)(ws + OFF_U2);
  int have = (ws_size >= TOTAL) ? 1 : 0;

  k_setup<<<103, 256, 0, stream>>>(phi, jmp, w2, b1, b2, w3, b3,
                                   l1p, thrp, tabp, b3p, (float4*)d1p);
  k_zq   <<<B_ * 4, 256, 0, stream>>>(x, l1p, thrp, jmp, zqp, d0p);
  k_u1f  <<<(B_ * P1) / 64, 64, 0, stream>>>(zqp, l1p, w1, b1, d0p, d1p, u1p, have);
  k_u2f  <<<(B_ * P2) / 64, 64, 0, stream>>>(u1p, w2, tabp, d1p, d2p, u2p, have);
  k_out  <<<(B_ * OW_ * OW_ + 255) / 256, 256, 0, stream>>>(b3p, d2p, u2p, w3, out);
}

// Round 3
// 144.735 us; speedup vs baseline: 3.1458x; 3.1458x over previous
//
#include <hip/hip_runtime.h>
#include <stdint.h>

// Problem constants
#define B_   128
#define C_   500
#define H_   16
#define P_   256      // 16*16 pixels per image
#define D_   192
#define C1O  300
#define H1   34
#define P1   (H1*H1)  // 1156
#define C2O  100
#define H2   36
#define P2   (H2*H2)  // 1296
#define C3O  3
#define H3   38
#define P3   (H3*H3)  // 1444
#define CROP 3
#define OW_  32
#define KTOP 30

#define NZQBLK (B_ * 4)                 // 512 zq blocks
#define NB3BLK ((P3 + 3) / 4)           // 361 base3 blocks (4 pixels each)

__device__ __forceinline__ float sgnf(float v){ return (v > 0.f) ? 1.f : ((v < 0.f) ? -1.f : 0.f); }

// tap-validity pattern for a position in a length-36 conv output coming from a
// length-34 input (k=3, stride=1 transposed conv).
__device__ __forceinline__ int pat36(int i){
  if (i == 0) return 0;       // {0}
  if (i == 1) return 1;       // {0,1}
  if (i <= 33) return 2;      // {0,1,2}
  if (i == 34) return 3;      // {1,2}
  return 4;                   // {2}
}

// =====================================================================
// k_setup: block-specialized, every block wave-parallel (round-1 shapes).
//   blocks 0..99   : base2 table row o=blk  (wave channel-reduce)
//   block  100     : l1 + thr (256 threads over channels)
//   blocks 101..164: zero d1+d2 region (313856 B, float4)
// =====================================================================
__global__ void k_setup(const float* __restrict__ phi, const float* __restrict__ jumpp,
                        const float* __restrict__ w2, const float* __restrict__ b1,
                        const float* __restrict__ b2,
                        float* __restrict__ l1, float* __restrict__ thr,
                        float* __restrict__ tab, float4* __restrict__ zero_region){
  const int blk = blockIdx.x;
  const int t = threadIdx.x;   // 256

  if (blk >= 101){             // ---- zeroing blocks ----
    const int idx0 = (blk - 101) * 256 + t;
    const int nvec = (B_ * P1 + B_ * P2) / 16;   // 19616
    float4 z = make_float4(0.f, 0.f, 0.f, 0.f);
    for (int i = idx0; i < nvec; i += 64 * 256) zero_region[i] = z;
    return;
  }

  if (blk == 100){             // ---- l1 / thr ----
    float J = jumpp[0];
    for (int c = t; c < C_; c += 256){
      float s = 0.f;
      for (int d = 0; d < D_; ++d) s += fabsf(phi[d * C_ + c]);
      s += 1e-12f;
      l1[c] = s;
      thr[c] = J * s;
    }
    return;
  }

  // ---- base2 row o = blk (0..99): wave 0 reduces over channels ----
  __shared__ float S[9];
  if (t < 64){
    const int o = blk;
    float acc[9] = {0,0,0,0,0,0,0,0,0};
    for (int c = t; c < C1O; c += 64){
      float a1 = fmaxf(b1[c], 0.f);
      const float* w = w2 + (c * C2O + o) * 9;
#pragma unroll
      for (int tap = 0; tap < 9; ++tap) acc[tap] += w[tap] * a1;
    }
#pragma unroll
    for (int tap = 0; tap < 9; ++tap)
      for (int off = 32; off; off >>= 1) acc[tap] += __shfl_down(acc[tap], off);
    if (t == 0){
#pragma unroll
      for (int tap = 0; tap < 9; ++tap) S[tap] = acc[tap];
    }
  }
  __syncthreads();
  if (t < 25){
    const int lo[5] = {0,0,0,1,2}, hi[5] = {0,1,2,2,2};
    int pr = t / 5, pc = t % 5;
    float s = b2[blk];
    for (int kh = lo[pr]; kh <= hi[pr]; ++kh)
      for (int kw = lo[pc]; kw <= hi[pc]; ++kw) s += S[kh * 3 + kw];
    tab[blk * 25 + t] = s;
  }
}

// =====================================================================
// k_zq_b3: block-specialized.
//   blocks 0..511   : float4 scan of x -> d0 flags (+cold topk/quant)
//   blocks 512..872 : base3 pixels, 4 per block (one per wave), reading tab
// =====================================================================
__global__ void k_zq_b3(const float* __restrict__ x, const float* __restrict__ l1,
                        const float* __restrict__ thr, const float* __restrict__ jumpp,
                        const float* __restrict__ tab, const float* __restrict__ w3,
                        const float* __restrict__ b3,
                        signed char* __restrict__ zq, unsigned char* __restrict__ d0,
                        float* __restrict__ base3){
  if (blockIdx.x >= NZQBLK){
    // ---------------- base3 part (round-1 k_base3 shape) ----------------
    const int wave = threadIdx.x >> 6, lane = threadIdx.x & 63;
    const int pix = (blockIdx.x - NZQBLK) * 4 + wave;
    if (pix >= P3) return;
    const int oh = pix / H3, ow = pix % H3;
    float acc[3] = {0, 0, 0};
    for (int c = lane; c < C2O; c += 64){
      const float* w = w3 + c * 27;  // [c][o][kh][kw]
#pragma unroll
      for (int kh = 0; kh < 3; ++kh){
        int ih = oh - kh; if (ih < 0 || ih >= H2) continue;
        int prr = pat36(ih) * 5;
#pragma unroll
        for (int kw = 0; kw < 3; ++kw){
          int iw = ow - kw; if (iw < 0 || iw >= H2) continue;
          float a2 = fmaxf(tab[c * 25 + prr + pat36(iw)], 0.f);
#pragma unroll
          for (int o = 0; o < 3; ++o) acc[o] += w[o * 9 + kh * 3 + kw] * a2;
        }
      }
    }
#pragma unroll
    for (int o = 0; o < 3; ++o){
      for (int off = 32; off; off >>= 1) acc[o] += __shfl_down(acc[o], off);
    }
    if (lane == 0){
#pragma unroll
      for (int o = 0; o < 3; ++o) base3[o * P3 + pix] = acc[o] + b3[o];
    }
    return;
  }

  // ---------------- zq part ----------------
  const int b = blockIdx.x >> 2;
  const int tile = (blockIdx.x & 3) * 64;
  const int t = threadIdx.x;            // 256
  const int q = t & 15, cg = t >> 4;    // pixel-quad, channel-group

  __shared__ unsigned char um[256];
  __shared__ unsigned char pixf[64];
  __shared__ int s_any;
  if (t == 0) s_any = 0;

  unsigned m = 0;
  const int pbase = tile + 4 * q;
  for (int c = cg; c < C_; c += 16){
    float tc = thr[c];
    const float4 v = *(const float4*)(x + ((size_t)(b * C_ + c)) * P_ + pbase);
    if (fabsf(v.x) >= tc) m |= 1u;
    if (fabsf(v.y) >= tc) m |= 2u;
    if (fabsf(v.z) >= tc) m |= 4u;
    if (fabsf(v.w) >= tc) m |= 8u;
  }
  um[t] = (unsigned char)m;
  __syncthreads();
  if (t < 16){
    unsigned mm = 0;
#pragma unroll
    for (int g = 0; g < 16; ++g) mm |= um[g * 16 + t];
#pragma unroll
    for (int j = 0; j < 4; ++j){
      unsigned char f = (unsigned char)((mm >> j) & 1u);
      pixf[4 * t + j] = f;
      d0[b * P_ + tile + 4 * t + j] = f;
    }
    if (mm) s_any = 1;                  // benign race, all write 1
  }
  __syncthreads();
  if (!s_any) return;

  // ---- cold path: exact top-30 (jax ties: lower index wins) + quant ----
  __shared__ float sx[C_];
  __shared__ unsigned char rm[C_];
  __shared__ unsigned long long red[4];
  __shared__ int sel[KTOP];
  float J = jumpp[0];
  for (int pp = 0; pp < 64; ++pp){
    if (!pixf[pp]) continue;
    int px = tile + pp;
    for (int c = t; c < C_; c += 256){ sx[c] = x[(b * C_ + c) * P_ + px]; rm[c] = 0; }
    __syncthreads();
    for (int it = 0; it < KTOP; ++it){
      unsigned long long best = 0ULL;
      for (int c = t; c < C_; c += 256){
        if (!rm[c]){
          unsigned long long key =
            ((unsigned long long)__float_as_uint(fabsf(sx[c])) << 32) |
            (unsigned int)(C_ - 1 - c);
          if (key > best) best = key;
        }
      }
      for (int off = 32; off; off >>= 1){
        unsigned long long o2 = __shfl_down(best, off);
        if (o2 > best) best = o2;
      }
      if ((t & 63) == 0) red[t >> 6] = best;
      __syncthreads();
      if (t == 0){
        unsigned long long mx = red[0];
        for (int wv = 1; wv < 4; ++wv) if (red[wv] > mx) mx = red[wv];
        int idx = C_ - 1 - (int)(mx & 0xffffffffULL);
        sel[it] = idx;
        rm[idx] = 1;
      }
      __syncthreads();
    }
    for (int c = t; c < C_; c += 256) zq[(b * C_ + c) * P_ + px] = 0;
    __syncthreads();
    if (t < KTOP){
      int c = sel[t];
      float z = sx[c];
      float r = z / l1[c];
      float qv = 0.5f * (sgnf(r - J) + sgnf(r + J));  // {-1,-0.5,0,0.5,1}
      int code = (int)(2.f * qv);                     // {-2,-1,0,1,2}
      if (code) zq[(b * C_ + c) * P_ + px] = (signed char)code;
    }
    __syncthreads();
  }
}

// =====================================================================
// k_u1f: fused scan1+u1. 64 threads/block = 1 wave; lane checks one
// level-1 pixel; ballot; compute u1 per dirty pixel with the whole wave.
// =====================================================================
__global__ void k_u1f(const signed char* __restrict__ zq, const float* __restrict__ l1,
                      const float* __restrict__ w1, const float* __restrict__ b1,
                      const unsigned char* __restrict__ d0,
                      unsigned char* __restrict__ d1, float* __restrict__ u1, int have){
  const int lane = threadIdx.x;   // 64
  const int pix0 = blockIdx.x * 64;
  const int tid = pix0 + lane;

  int b = tid / P1, p1 = tid - b * P1;
  int ih = p1 / H1, iw = p1 - ih * H1;
  int h0 = max(0, (ih - 2) >> 1), h1v = min(H_ - 1, ih >> 1);
  int w0 = max(0, (iw - 2) >> 1), w1v = min(H_ - 1, iw >> 1);
  int any = 0;
  for (int h = h0; h <= h1v; ++h)
    for (int w = w0; w <= w1v; ++w)
      any |= d0[b * P_ + h * H_ + w];
  unsigned long long mask = __ballot(any != 0);
  if (!mask) return;
  if (any) d1[tid] = 1;

  while (mask){
    int pp = __ffsll((long long)mask) - 1;
    mask &= mask - 1;
    int pix = pix0 + pp;
    int bb = pix / P1, pq = pix - bb * P1;
    int oih = pq / H1, oiw = pq - oih * H1;
    float acc[5] = {0,0,0,0,0};
    int hh0 = max(0, (oih - 2) >> 1), hh1 = min(H_ - 1, oih >> 1);
    int ww0 = max(0, (oiw - 2) >> 1), ww1 = min(H_ - 1, oiw >> 1);
    for (int h = hh0; h <= hh1; ++h)
      for (int w = ww0; w <= ww1; ++w){
        if (!d0[bb * P_ + h * H_ + w]) continue;
        int kh = oih - 2 * h, kw = oiw - 2 * w;
        const signed char* zp = zq + (size_t)(bb * C_) * P_ + h * H_ + w;
        for (int c = 0; c < C_; ++c){
          int code = zp[(size_t)c * P_];
          if (!code) continue;
          float val = 0.5f * (float)code * l1[c];
          const float* wp = w1 + (size_t)(c * C1O) * 16 + kh * 4 + kw;
#pragma unroll
          for (int j = 0; j < 5; ++j){
            int c1 = j * 64 + lane;
            if (c1 < C1O) acc[j] += wp[(size_t)c1 * 16] * val;
          }
        }
      }
    if (have){
#pragma unroll
      for (int j = 0; j < 5; ++j){
        int c1 = j * 64 + lane;
        if (c1 < C1O){
          float bb1 = b1[c1];
          u1[(size_t)(bb * C1O + c1) * P1 + pq] = fmaxf(bb1 + acc[j], 0.f) - fmaxf(bb1, 0.f);
        }
      }
    }
  }
}

// =====================================================================
// k_u2f: fused scan2+u2, same structure.
// =====================================================================
__global__ void k_u2f(const float* __restrict__ u1, const float* __restrict__ w2,
                      const float* __restrict__ tab, const unsigned char* __restrict__ d1,
                      unsigned char* __restrict__ d2, float* __restrict__ u2, int have){
  const int lane = threadIdx.x;   // 64
  const int pix0 = blockIdx.x * 64;
  const int tid = pix0 + lane;

  int b = tid / P2, p2 = tid - b * P2;
  int oh = p2 / H2, ow = p2 - oh * H2;
  int any = 0;
  for (int kh = 0; kh < 3; ++kh){
    int ih = oh - kh; if (ih < 0 || ih >= H1) continue;
    for (int kw = 0; kw < 3; ++kw){
      int iw = ow - kw; if (iw < 0 || iw >= H1) continue;
      any |= d1[b * P1 + ih * H1 + iw];
    }
  }
  unsigned long long mask = __ballot(any != 0);
  if (!mask) return;
  if (any) d2[tid] = 1;

  while (mask){
    int pp = __ffsll((long long)mask) - 1;
    mask &= mask - 1;
    int pix = pix0 + pp;
    int bb = pix / P2, pq = pix - bb * P2;
    int ooh = pq / H2, oow = pq - ooh * H2;
    float acc[2] = {0,0};
    for (int kh = 0; kh < 3; ++kh){
      int ih = ooh - kh; if (ih < 0 || ih >= H1) continue;
      for (int kw = 0; kw < 3; ++kw){
        int iw = oow - kw; if (iw < 0 || iw >= H1) continue;
        if (!d1[bb * P1 + ih * H1 + iw]) continue;
        const float* up = u1 + (size_t)(bb * C1O) * P1 + ih * H1 + iw;
        const float* wb = w2 + kh * 3 + kw;
        for (int c1 = 0; c1 < C1O; ++c1){
          float uv = up[(size_t)c1 * P1];
          if (uv == 0.f) continue;
          const float* wp = wb + (size_t)(c1 * C2O) * 9;
#pragma unroll
          for (int j = 0; j < 2; ++j){
            int c2 = j * 64 + lane;
            if (c2 < C2O) acc[j] += wp[(size_t)c2 * 9] * uv;
          }
        }
      }
    }
    if (have){
      int pr = pat36(ooh) * 5 + pat36(oow);
#pragma unroll
      for (int j = 0; j < 2; ++j){
        int c2 = j * 64 + lane;
        if (c2 < C2O){
          float bs = tab[c2 * 25 + pr];
          u2[(size_t)(bb * C2O + c2) * P2 + pq] = fmaxf(bs + acc[j], 0.f) - fmaxf(bs, 0.f);
        }
      }
    }
  }
}

// ----------------------------------------------------------- final output
__global__ void k_out(const float* __restrict__ base3, const unsigned char* __restrict__ d2,
                      const float* __restrict__ u2, const float* __restrict__ w3,
                      float* __restrict__ out){
  int tid = blockIdx.x * blockDim.x + threadIdx.x;
  if (tid >= B_ * OW_ * OW_) return;
  int b = tid >> 10;
  int rc = tid & 1023;
  int r = rc >> 5, cc = rc & 31;
  int oh = r + CROP, ow = cc + CROP;   // all 9 taps in-bounds
  int any = 0;
#pragma unroll
  for (int kh = 0; kh < 3; ++kh)
#pragma unroll
    for (int kw = 0; kw < 3; ++kw)
      any |= d2[b * P2 + (oh - kh) * H2 + (ow - kw)];
  if (!any){
#pragma unroll
    for (int o = 0; o < 3; ++o)
      out[((b * 3 + o) * OW_ + r) * OW_ + cc] = fmaxf(base3[o * P3 + oh * H3 + ow], 0.f);
    return;
  }
  float acc[3];
#pragma unroll
  for (int o = 0; o < 3; ++o) acc[o] = base3[o * P3 + oh * H3 + ow];
  for (int kh = 0; kh < 3; ++kh){
    int ih = oh - kh;
    for (int kw = 0; kw < 3; ++kw){
      int iw = ow - kw;
      if (!d2[b * P2 + ih * H2 + iw]) continue;
      const float* up = u2 + (size_t)(b * C2O) * P2 + ih * H2 + iw;
      const float* wb = w3 + kh * 3 + kw;
      for (int c2 = 0; c2 < C2O; ++c2){
        float uv = up[(size_t)c2 * P2];
        if (uv == 0.f) continue;
        const float* wp = wb + c2 * 27;
#pragma unroll
        for (int o = 0; o < 3; ++o) acc[o] += wp[o * 9] * uv;
      }
    }
  }
#pragma unroll
  for (int o = 0; o < 3; ++o)
    out[((b * 3 + o) * OW_ + r) * OW_ + cc] = fmaxf(acc[o], 0.f);
}

extern "C" void kernel_launch(void* const* d_in, const int* in_sizes, int n_in,
                              void* d_out, int out_size, void* d_ws, size_t ws_size,
                              hipStream_t stream){
  const float* x   = (const float*)d_in[0];
  const float* phi = (const float*)d_in[1];
  const float* jmp = (const float*)d_in[2];
  const float* w1  = (const float*)d_in[3];
  const float* b1  = (const float*)d_in[4];
  const float* w2  = (const float*)d_in[5];
  const float* b2  = (const float*)d_in[6];
  const float* w3  = (const float*)d_in[7];
  const float* b3  = (const float*)d_in[8];
  float* out = (float*)d_out;
  char* ws = (char*)d_ws;

  // workspace layout (bytes, 16B-aligned)
  constexpr size_t OFF_L1  = 0;                                  // 500 f32
  constexpr size_t OFF_THR = OFF_L1  + 2048;                     // 500 f32
  constexpr size_t OFF_TAB = OFF_THR + 2048;                     // 2500 f32
  constexpr size_t OFF_B3  = OFF_TAB + 10240;                    // 4332 f32
  constexpr size_t OFF_D0  = OFF_B3  + 17344;                    // 32768 u8
  constexpr size_t OFF_D1  = OFF_D0  + (size_t)B_ * P_;          // u8 (16B aligned)
  constexpr size_t OFF_D2  = OFF_D1  + (size_t)B_ * P1;          // u8 (contiguous w/ D1)
  constexpr size_t OFF_ZQ  = OFF_D2  + (size_t)B_ * P2;          // i8 codes
  constexpr size_t OFF_U1  = OFF_ZQ  + (size_t)B_ * C_ * P_;
  constexpr size_t OFF_U2  = OFF_U1  + (size_t)B_ * C1O * P1 * 4;
  constexpr size_t TOTAL   = OFF_U2  + (size_t)B_ * C2O * P2 * 4;

  float* l1p  = (float*)(ws + OFF_L1);
  float* thrp = (float*)(ws + OFF_THR);
  float* tabp = (float*)(ws + OFF_TAB);
  float* b3p  = (float*)(ws + OFF_B3);
  unsigned char* d0p = (unsigned char*)(ws + OFF_D0);
  unsigned char* d1p = (unsigned char*)(ws + OFF_D1);
  unsigned char* d2p = (unsigned char*)(ws + OFF_D2);
  signed char* zqp = (signed char*)(ws + OFF_ZQ);
  float* u1p = (float*)(ws + OFF_U1);
  float* u2p = (float*)(ws + OFF_U2);
  int have = (ws_size >= TOTAL) ? 1 : 0;

  k_setup<<<165, 256, 0, stream>>>(phi, jmp, w2, b1, b2, l1p, thrp, tabp, (float4*)d1p);
  k_zq_b3<<<NZQBLK + NB3BLK, 256, 0, stream>>>(x, l1p, thrp, jmp, tabp, w3, b3,
                                               zqp, d0p, b3p);
  k_u1f  <<<(B_ * P1) / 64, 64, 0, stream>>>(zqp, l1p, w1, b1, d0p, d1p, u1p, have);
  k_u2f  <<<(B_ * P2) / 64, 64, 0, stream>>>(u1p, w2, tabp, d1p, d2p, u2p, have);
  k_out  <<<(B_ * OW_ * OW_ + 255) / 256, 256, 0, stream>>>(b3p, d2p, u2p, w3, out);
}

// Round 4
// 132.905 us; speedup vs baseline: 3.4258x; 1.0890x over previous
//
#include <hip/hip_runtime.h>
#include <stdint.h>

// Problem constants
#define B_   128
#define C_   500
#define H_   16
#define P_   256      // 16*16 pixels per image
#define D_   192
#define C1O  300
#define H1   34
#define P1   (H1*H1)  // 1156
#define C2O  100
#define H2   36
#define P2   (H2*H2)  // 1296
#define C3O  3
#define H3   38
#define P3   (H3*H3)  // 1444
#define CROP 3
#define OW_  32
#define KTOP 30

#define NL1B   16                       // l1/thr blocks (32 channels each)
#define NZQBLK (B_ * 4)                 // 512 zq blocks
#define NB3BLK ((P3 + 3) / 4)           // 361 base3 blocks (4 pixels each)

__device__ __forceinline__ float sgnf(float v){ return (v > 0.f) ? 1.f : ((v < 0.f) ? -1.f : 0.f); }

// tap-validity pattern for a position in a length-36 conv output coming from a
// length-34 input (k=3, stride=1 transposed conv).
__device__ __forceinline__ int pat36(int i){
  if (i == 0) return 0;       // {0}
  if (i == 1) return 1;       // {0,1}
  if (i <= 33) return 2;      // {0,1,2}
  if (i == 34) return 3;      // {1,2}
  return 4;                   // {2}
}

// =====================================================================
// k_setup: block-specialized, every block wave-parallel.
//   blocks 0..15    : l1 + thr, 32 channels/block (8 d-groups LDS-reduced)
//   blocks 16..115  : base2 table row o=blk-16 (wave channel-reduce)
//   blocks 116..179 : zero cnt+d1+d2 region (313872 B, float4)
// =====================================================================
__global__ void k_setup(const float* __restrict__ phi, const float* __restrict__ jumpp,
                        const float* __restrict__ w2, const float* __restrict__ b1,
                        const float* __restrict__ b2,
                        float* __restrict__ l1, float* __restrict__ thr,
                        float* __restrict__ tab, float4* __restrict__ zero_region){
  const int blk = blockIdx.x;
  const int t = threadIdx.x;   // 256

  if (blk >= NL1B + 100){      // ---- zeroing blocks ----
    const int idx0 = (blk - (NL1B + 100)) * 256 + t;
    const int nvec = (16 + B_ * P1 + B_ * P2) / 16;   // 19617
    float4 z = make_float4(0.f, 0.f, 0.f, 0.f);
    for (int i = idx0; i < nvec; i += 64 * 256) zero_region[i] = z;
    return;
  }

  if (blk < NL1B){             // ---- l1 / thr: 32 channels, 8 d-groups ----
    __shared__ float red[8][32];
    const int cl = t & 31, dg = t >> 5;      // channel-in-block, d-group
    const int c = blk * 32 + cl;
    float s = 0.f;
    if (c < C_){
      const int d0 = dg * 24;
#pragma unroll 4
      for (int d = d0; d < d0 + 24; ++d) s += fabsf(phi[d * C_ + c]);
    }
    red[dg][cl] = s;
    __syncthreads();
    if (t < 32){
      int cc = blk * 32 + t;
      if (cc < C_){
        float sum = 1e-12f;
#pragma unroll
        for (int g = 0; g < 8; ++g) sum += red[g][t];
        l1[cc] = sum;
        thr[cc] = jumpp[0] * sum;
      }
    }
    return;
  }

  // ---- base2 row o = blk-16 (0..99): wave 0 reduces over channels ----
  __shared__ float S[9];
  const int o = blk - NL1B;
  if (t < 64){
    float acc[9] = {0,0,0,0,0,0,0,0,0};
    for (int c = t; c < C1O; c += 64){
      float a1 = fmaxf(b1[c], 0.f);
      const float* w = w2 + (c * C2O + o) * 9;
#pragma unroll
      for (int tap = 0; tap < 9; ++tap) acc[tap] += w[tap] * a1;
    }
#pragma unroll
    for (int tap = 0; tap < 9; ++tap)
      for (int off = 32; off; off >>= 1) acc[tap] += __shfl_down(acc[tap], off);
    if (t == 0){
#pragma unroll
      for (int tap = 0; tap < 9; ++tap) S[tap] = acc[tap];
    }
  }
  __syncthreads();
  if (t < 25){
    const int lo[5] = {0,0,0,1,2}, hi[5] = {0,1,2,2,2};
    int pr = t / 5, pc = t % 5;
    float s = b2[o];
    for (int kh = lo[pr]; kh <= hi[pr]; ++kh)
      for (int kw = lo[pc]; kw <= hi[pc]; ++kw) s += S[kh * 3 + kw];
    tab[o * 25 + t] = s;
  }
}

// =====================================================================
// k_zq_b3: block-specialized.
//   blocks 0..511   : float4 scan of x -> d0 flags (+cold topk/quant);
//                     bumps cnt[0] if any pixel dirty.
//   blocks 512..872 : base3 pixels, 4 per block (one per wave)
// =====================================================================
__global__ void k_zq_b3(const float* __restrict__ x, const float* __restrict__ l1,
                        const float* __restrict__ thr, const float* __restrict__ jumpp,
                        const float* __restrict__ tab, const float* __restrict__ w3,
                        const float* __restrict__ b3,
                        signed char* __restrict__ zq, unsigned char* __restrict__ d0,
                        float* __restrict__ base3, int* __restrict__ cnt){
  if (blockIdx.x >= NZQBLK){
    // ---------------- base3 part ----------------
    const int wave = threadIdx.x >> 6, lane = threadIdx.x & 63;
    const int pix = (blockIdx.x - NZQBLK) * 4 + wave;
    if (pix >= P3) return;
    const int oh = pix / H3, ow = pix % H3;
    float acc[3] = {0, 0, 0};
    for (int c = lane; c < C2O; c += 64){
      const float* w = w3 + c * 27;  // [c][o][kh][kw]
#pragma unroll
      for (int kh = 0; kh < 3; ++kh){
        int ih = oh - kh; if (ih < 0 || ih >= H2) continue;
        int prr = pat36(ih) * 5;
#pragma unroll
        for (int kw = 0; kw < 3; ++kw){
          int iw = ow - kw; if (iw < 0 || iw >= H2) continue;
          float a2 = fmaxf(tab[c * 25 + prr + pat36(iw)], 0.f);
#pragma unroll
          for (int o = 0; o < 3; ++o) acc[o] += w[o * 9 + kh * 3 + kw] * a2;
        }
      }
    }
#pragma unroll
    for (int o = 0; o < 3; ++o){
      for (int off = 32; off; off >>= 1) acc[o] += __shfl_down(acc[o], off);
    }
    if (lane == 0){
#pragma unroll
      for (int o = 0; o < 3; ++o) base3[o * P3 + pix] = acc[o] + b3[o];
    }
    return;
  }

  // ---------------- zq part ----------------
  const int b = blockIdx.x >> 2;
  const int tile = (blockIdx.x & 3) * 64;
  const int t = threadIdx.x;            // 256
  const int q = t & 15, cg = t >> 4;    // pixel-quad, channel-group

  __shared__ unsigned char um[256];
  __shared__ unsigned char pixf[64];
  __shared__ int s_any;
  if (t == 0) s_any = 0;

  unsigned m = 0;
  const int pbase = tile + 4 * q;
  for (int c = cg; c < C_; c += 16){
    float tc = thr[c];
    const float4 v = *(const float4*)(x + ((size_t)(b * C_ + c)) * P_ + pbase);
    if (fabsf(v.x) >= tc) m |= 1u;
    if (fabsf(v.y) >= tc) m |= 2u;
    if (fabsf(v.z) >= tc) m |= 4u;
    if (fabsf(v.w) >= tc) m |= 8u;
  }
  um[t] = (unsigned char)m;
  __syncthreads();
  if (t < 16){
    unsigned mm = 0;
#pragma unroll
    for (int g = 0; g < 16; ++g) mm |= um[g * 16 + t];
#pragma unroll
    for (int j = 0; j < 4; ++j){
      unsigned char f = (unsigned char)((mm >> j) & 1u);
      pixf[4 * t + j] = f;
      d0[b * P_ + tile + 4 * t + j] = f;
    }
    if (mm) s_any = 1;                  // benign race, all write 1
  }
  __syncthreads();
  if (t == 0 && s_any) atomicAdd(cnt, 1);
  if (!s_any) return;

  // ---- cold path: exact top-30 (jax ties: lower index wins) + quant ----
  __shared__ float sx[C_];
  __shared__ unsigned char rm[C_];
  __shared__ unsigned long long red[4];
  __shared__ int sel[KTOP];
  float J = jumpp[0];
  for (int pp = 0; pp < 64; ++pp){
    if (!pixf[pp]) continue;
    int px = tile + pp;
    for (int c = t; c < C_; c += 256){ sx[c] = x[(b * C_ + c) * P_ + px]; rm[c] = 0; }
    __syncthreads();
    for (int it = 0; it < KTOP; ++it){
      unsigned long long best = 0ULL;
      for (int c = t; c < C_; c += 256){
        if (!rm[c]){
          unsigned long long key =
            ((unsigned long long)__float_as_uint(fabsf(sx[c])) << 32) |
            (unsigned int)(C_ - 1 - c);
          if (key > best) best = key;
        }
      }
      for (int off = 32; off; off >>= 1){
        unsigned long long o2 = __shfl_down(best, off);
        if (o2 > best) best = o2;
      }
      if ((t & 63) == 0) red[t >> 6] = best;
      __syncthreads();
      if (t == 0){
        unsigned long long mx = red[0];
        for (int wv = 1; wv < 4; ++wv) if (red[wv] > mx) mx = red[wv];
        int idx = C_ - 1 - (int)(mx & 0xffffffffULL);
        sel[it] = idx;
        rm[idx] = 1;
      }
      __syncthreads();
    }
    for (int c = t; c < C_; c += 256) zq[(b * C_ + c) * P_ + px] = 0;
    __syncthreads();
    if (t < KTOP){
      int c = sel[t];
      float z = sx[c];
      float r = z / l1[c];
      float qv = 0.5f * (sgnf(r - J) + sgnf(r + J));  // {-1,-0.5,0,0.5,1}
      int code = (int)(2.f * qv);                     // {-2,-1,0,1,2}
      if (code) zq[(b * C_ + c) * P_ + px] = (signed char)code;
    }
    __syncthreads();
  }
}

// =====================================================================
// k_u1f: fused scan1+u1. 256 threads = 4 waves, each wave owns a 64-pixel
// chunk. Scalar early-exit on cnt[0]==0. Bumps cnt[1] if dirty.
// =====================================================================
__global__ void k_u1f(const signed char* __restrict__ zq, const float* __restrict__ l1,
                      const float* __restrict__ w1, const float* __restrict__ b1,
                      const unsigned char* __restrict__ d0, const int* __restrict__ cnt,
                      int* __restrict__ cnt1,
                      unsigned char* __restrict__ d1, float* __restrict__ u1, int have){
  if (cnt[0] == 0) return;
  const int wave = threadIdx.x >> 6, lane = threadIdx.x & 63;
  const int pix0 = (blockIdx.x * 4 + wave) * 64;
  const int tid = pix0 + lane;

  int b = tid / P1, p1 = tid - b * P1;
  int ih = p1 / H1, iw = p1 - ih * H1;
  int h0 = max(0, (ih - 2) >> 1), h1v = min(H_ - 1, ih >> 1);
  int w0 = max(0, (iw - 2) >> 1), w1v = min(H_ - 1, iw >> 1);
  int any = 0;
  for (int h = h0; h <= h1v; ++h)
    for (int w = w0; w <= w1v; ++w)
      any |= d0[b * P_ + h * H_ + w];
  unsigned long long mask = __ballot(any != 0);
  if (!mask) return;
  if (any) d1[tid] = 1;
  if (lane == 0) atomicAdd(cnt1, 1);

  while (mask){
    int pp = __ffsll((long long)mask) - 1;
    mask &= mask - 1;
    int pix = pix0 + pp;
    int bb = pix / P1, pq = pix - bb * P1;
    int oih = pq / H1, oiw = pq - oih * H1;
    float acc[5] = {0,0,0,0,0};
    int hh0 = max(0, (oih - 2) >> 1), hh1 = min(H_ - 1, oih >> 1);
    int ww0 = max(0, (oiw - 2) >> 1), ww1 = min(H_ - 1, oiw >> 1);
    for (int h = hh0; h <= hh1; ++h)
      for (int w = ww0; w <= ww1; ++w){
        if (!d0[bb * P_ + h * H_ + w]) continue;
        int kh = oih - 2 * h, kw = oiw - 2 * w;
        const signed char* zp = zq + (size_t)(bb * C_) * P_ + h * H_ + w;
        for (int c = 0; c < C_; ++c){
          int code = zp[(size_t)c * P_];
          if (!code) continue;
          float val = 0.5f * (float)code * l1[c];
          const float* wp = w1 + (size_t)(c * C1O) * 16 + kh * 4 + kw;
#pragma unroll
          for (int j = 0; j < 5; ++j){
            int c1 = j * 64 + lane;
            if (c1 < C1O) acc[j] += wp[(size_t)c1 * 16] * val;
          }
        }
      }
    if (have){
#pragma unroll
      for (int j = 0; j < 5; ++j){
        int c1 = j * 64 + lane;
        if (c1 < C1O){
          float bb1 = b1[c1];
          u1[(size_t)(bb * C1O + c1) * P1 + pq] = fmaxf(bb1 + acc[j], 0.f) - fmaxf(bb1, 0.f);
        }
      }
    }
  }
}

// =====================================================================
// k_u2f: fused scan2+u2, same structure. Early-exit on cnt[1]==0.
// =====================================================================
__global__ void k_u2f(const float* __restrict__ u1, const float* __restrict__ w2,
                      const float* __restrict__ tab, const unsigned char* __restrict__ d1,
                      const int* __restrict__ cnt1, int* __restrict__ cnt2,
                      unsigned char* __restrict__ d2, float* __restrict__ u2, int have){
  if (cnt1[0] == 0) return;
  const int wave = threadIdx.x >> 6, lane = threadIdx.x & 63;
  const int pix0 = (blockIdx.x * 4 + wave) * 64;
  const int tid = pix0 + lane;

  int b = tid / P2, p2 = tid - b * P2;
  int oh = p2 / H2, ow = p2 - oh * H2;
  int any = 0;
  for (int kh = 0; kh < 3; ++kh){
    int ih = oh - kh; if (ih < 0 || ih >= H1) continue;
    for (int kw = 0; kw < 3; ++kw){
      int iw = ow - kw; if (iw < 0 || iw >= H1) continue;
      any |= d1[b * P1 + ih * H1 + iw];
    }
  }
  unsigned long long mask = __ballot(any != 0);
  if (!mask) return;
  if (any) d2[tid] = 1;
  if (lane == 0) atomicAdd(cnt2, 1);

  while (mask){
    int pp = __ffsll((long long)mask) - 1;
    mask &= mask - 1;
    int pix = pix0 + pp;
    int bb = pix / P2, pq = pix - bb * P2;
    int ooh = pq / H2, oow = pq - ooh * H2;
    float acc[2] = {0,0};
    for (int kh = 0; kh < 3; ++kh){
      int ih = ooh - kh; if (ih < 0 || ih >= H1) continue;
      for (int kw = 0; kw < 3; ++kw){
        int iw = oow - kw; if (iw < 0 || iw >= H1) continue;
        if (!d1[bb * P1 + ih * H1 + iw]) continue;
        const float* up = u1 + (size_t)(bb * C1O) * P1 + ih * H1 + iw;
        const float* wb = w2 + kh * 3 + kw;
        for (int c1 = 0; c1 < C1O; ++c1){
          float uv = up[(size_t)c1 * P1];
          if (uv == 0.f) continue;
          const float* wp = wb + (size_t)(c1 * C2O) * 9;
#pragma unroll
          for (int j = 0; j < 2; ++j){
            int c2 = j * 64 + lane;
            if (c2 < C2O) acc[j] += wp[(size_t)c2 * 9] * uv;
          }
        }
      }
    }
    if (have){
      int pr = pat36(ooh) * 5 + pat36(oow);
#pragma unroll
      for (int j = 0; j < 2; ++j){
        int c2 = j * 64 + lane;
        if (c2 < C2O){
          float bs = tab[c2 * 25 + pr];
          u2[(size_t)(bb * C2O + c2) * P2 + pq] = fmaxf(bs + acc[j], 0.f) - fmaxf(bs, 0.f);
        }
      }
    }
  }
}

// ----------------------------------------------------------- final output
// One float4 store per thread: thread owns (b, o, row r, 4 cols).
__global__ void k_out(const float* __restrict__ base3, const unsigned char* __restrict__ d2,
                      const float* __restrict__ u2, const float* __restrict__ w3,
                      const int* __restrict__ cnt2, float* __restrict__ out){
  int tid = blockIdx.x * blockDim.x + threadIdx.x;   // 98304 threads
  if (tid >= B_ * 3 * OW_ * (OW_ / 4)) return;
  const int perimg = 3 * OW_ * (OW_ / 4);            // 768
  int b = tid / perimg;
  int rem = tid - b * perimg;
  int o = rem >> 8;                                  // rem/256
  int rr = rem & 255;
  int r = rr >> 3, q4 = rr & 7;
  int oh = r + CROP;
  int ow0 = q4 * 4 + CROP;
  const float* bp = base3 + o * P3 + oh * H3 + ow0;

  float4 res;
  float* rp = &res.x;
  if (cnt2[0] == 0){
#pragma unroll
    for (int j = 0; j < 4; ++j) rp[j] = fmaxf(bp[j], 0.f);
  } else {
#pragma unroll
    for (int j = 0; j < 4; ++j){
      int ow = ow0 + j;
      float acc = bp[j];
      for (int kh = 0; kh < 3; ++kh){
        int ih = oh - kh;
        for (int kw = 0; kw < 3; ++kw){
          int iw = ow - kw;
          if (!d2[b * P2 + ih * H2 + iw]) continue;
          const float* up = u2 + (size_t)(b * C2O) * P2 + ih * H2 + iw;
          const float* wp = w3 + o * 9 + kh * 3 + kw;
          for (int c2 = 0; c2 < C2O; ++c2){
            float uv = up[(size_t)c2 * P2];
            if (uv != 0.f) acc += wp[c2 * 27] * uv;
          }
        }
      }
      rp[j] = fmaxf(acc, 0.f);
    }
  }
  *(float4*)(out + ((size_t)(b * 3 + o) * OW_ + r) * OW_ + q4 * 4) = res;
}

extern "C" void kernel_launch(void* const* d_in, const int* in_sizes, int n_in,
                              void* d_out, int out_size, void* d_ws, size_t ws_size,
                              hipStream_t stream){
  const float* x   = (const float*)d_in[0];
  const float* phi = (const float*)d_in[1];
  const float* jmp = (const float*)d_in[2];
  const float* w1  = (const float*)d_in[3];
  const float* b1  = (const float*)d_in[4];
  const float* w2  = (const float*)d_in[5];
  const float* b2  = (const float*)d_in[6];
  const float* w3  = (const float*)d_in[7];
  const float* b3  = (const float*)d_in[8];
  float* out = (float*)d_out;
  char* ws = (char*)d_ws;

  // workspace layout (bytes, 16B-aligned)
  constexpr size_t OFF_L1  = 0;                                  // 500 f32
  constexpr size_t OFF_THR = OFF_L1  + 2048;
  constexpr size_t OFF_TAB = OFF_THR + 2048;                     // 2500 f32
  constexpr size_t OFF_B3  = OFF_TAB + 10240;                    // 4332 f32
  constexpr size_t OFF_D0  = OFF_B3  + 17344;                    // 32768 u8
  constexpr size_t OFF_CNT = OFF_D0  + (size_t)B_ * P_;          // 4 i32 (16 B)
  constexpr size_t OFF_D1  = OFF_CNT + 16;                       // u8, zeroed w/ cnt
  constexpr size_t OFF_D2  = OFF_D1  + (size_t)B_ * P1;          // u8, contiguous
  constexpr size_t OFF_ZQ  = OFF_D2  + (size_t)B_ * P2;          // i8 codes
  constexpr size_t OFF_U1  = OFF_ZQ  + (size_t)B_ * C_ * P_;
  constexpr size_t OFF_U2  = OFF_U1  + (size_t)B_ * C1O * P1 * 4;
  constexpr size_t TOTAL   = OFF_U2  + (size_t)B_ * C2O * P2 * 4;

  float* l1p  = (float*)(ws + OFF_L1);
  float* thrp = (float*)(ws + OFF_THR);
  float* tabp = (float*)(ws + OFF_TAB);
  float* b3p  = (float*)(ws + OFF_B3);
  unsigned char* d0p = (unsigned char*)(ws + OFF_D0);
  int* cntp = (int*)(ws + OFF_CNT);                  // [0]=d0, [1]=d1, [2]=d2
  unsigned char* d1p = (unsigned char*)(ws + OFF_D1);
  unsigned char* d2p = (unsigned char*)(ws + OFF_D2);
  signed char* zqp = (signed char*)(ws + OFF_ZQ);
  float* u1p = (float*)(ws + OFF_U1);
  float* u2p = (float*)(ws + OFF_U2);
  int have = (ws_size >= TOTAL) ? 1 : 0;

  k_setup<<<NL1B + 100 + 64, 256, 0, stream>>>(phi, jmp, w2, b1, b2,
                                               l1p, thrp, tabp, (float4*)cntp);
  k_zq_b3<<<NZQBLK + NB3BLK, 256, 0, stream>>>(x, l1p, thrp, jmp, tabp, w3, b3,
                                               zqp, d0p, b3p, cntp);
  k_u1f  <<<(B_ * P1) / 256, 256, 0, stream>>>(zqp, l1p, w1, b1, d0p, cntp, cntp + 1,
                                               d1p, u1p, have);
  k_u2f  <<<(B_ * P2) / 256, 256, 0, stream>>>(u1p, w2, tabp, d1p, cntp + 1, cntp + 2,
                                               d2p, u2p, have);
  k_out  <<<(B_ * 3 * OW_ * (OW_ / 4) + 255) / 256, 256, 0, stream>>>(
      b3p, d2p, u2p, w3, cntp + 2, out);
}

// Round 5
// 129.596 us; speedup vs baseline: 3.5133x; 1.0255x over previous
//
#include <hip/hip_runtime.h>
#include <stdint.h>

// Problem constants
#define B_   128
#define C_   500
#define H_   16
#define P_   256      // 16*16 pixels per image
#define D_   192
#define C1O  300
#define H1   34
#define P1   (H1*H1)  // 1156
#define C2O  100
#define H2   36
#define P2   (H2*H2)  // 1296
#define C3O  3
#define H3   38
#define P3   (H3*H3)  // 1444
#define CROP 3
#define OW_  32
#define KTOP 30

#define NL1B   16                       // l1/thr blocks (32 channels each)
#define NZQBLK (B_ * 4)                 // 512 scan blocks
#define NB3BLK ((P3 + 3) / 4)           // 361 base3 blocks (4 pixels each)

__device__ __forceinline__ float sgnf(float v){ return (v > 0.f) ? 1.f : ((v < 0.f) ? -1.f : 0.f); }

// tap-validity pattern for a position in a length-36 conv output coming from a
// length-34 input (k=3, stride=1 transposed conv).
__device__ __forceinline__ int pat36(int i){
  if (i == 0) return 0;       // {0}
  if (i == 1) return 1;       // {0,1}
  if (i <= 33) return 2;      // {0,1,2}
  if (i == 34) return 3;      // {1,2}
  return 4;                   // {2}
}

// =====================================================================
// k_setup: block-specialized, every block wave-parallel.
//   blocks 0..15   : l1 + thr, 32 channels/block (8 d-groups LDS-reduced)
//   blocks 16..115 : base2 table row o=blk-16 (wave channel-reduce)
// =====================================================================
__global__ void k_setup(const float* __restrict__ phi, const float* __restrict__ jumpp,
                        const float* __restrict__ w2, const float* __restrict__ b1,
                        const float* __restrict__ b2,
                        float* __restrict__ l1, float* __restrict__ thr,
                        float* __restrict__ tab){
  const int blk = blockIdx.x;
  const int t = threadIdx.x;   // 256

  if (blk < NL1B){             // ---- l1 / thr: 32 channels, 8 d-groups ----
    __shared__ float red[8][32];
    const int cl = t & 31, dg = t >> 5;      // channel-in-block, d-group
    const int c = blk * 32 + cl;
    float s = 0.f;
    if (c < C_){
      const int d0 = dg * 24;
#pragma unroll 4
      for (int d = d0; d < d0 + 24; ++d) s += fabsf(phi[d * C_ + c]);
    }
    red[dg][cl] = s;
    __syncthreads();
    if (t < 32){
      int cc = blk * 32 + t;
      if (cc < C_){
        float sum = 1e-12f;
#pragma unroll
        for (int g = 0; g < 8; ++g) sum += red[g][t];
        l1[cc] = sum;
        thr[cc] = jumpp[0] * sum;
      }
    }
    return;
  }

  // ---- base2 row o = blk-16 (0..99): wave 0 reduces over channels ----
  __shared__ float S[9];
  const int o = blk - NL1B;
  if (t < 64){
    float acc[9] = {0,0,0,0,0,0,0,0,0};
    for (int c = t; c < C1O; c += 64){
      float a1 = fmaxf(b1[c], 0.f);
      const float* w = w2 + (c * C2O + o) * 9;
#pragma unroll
      for (int tap = 0; tap < 9; ++tap) acc[tap] += w[tap] * a1;
    }
#pragma unroll
    for (int tap = 0; tap < 9; ++tap)
      for (int off = 32; off; off >>= 1) acc[tap] += __shfl_down(acc[tap], off);
    if (t == 0){
#pragma unroll
      for (int tap = 0; tap < 9; ++tap) S[tap] = acc[tap];
    }
  }
  __syncthreads();
  if (t < 25){
    const int lo[5] = {0,0,0,1,2}, hi[5] = {0,1,2,2,2};
    int pr = t / 5, pc = t % 5;
    float s = b2[o];
    for (int kh = lo[pr]; kh <= hi[pr]; ++kh)
      for (int kw = lo[pc]; kw <= hi[pc]; ++kw) s += S[kh * 3 + kw];
    tab[o * 25 + t] = s;
  }
}

// =====================================================================
// k_scan_b3: block-specialized.
//   blocks 0..511   : pure streaming float4 scan of x -> d0 flags
//   blocks 512..872 : base3 pixels, 4 per block (one per wave)
// =====================================================================
__global__ void k_scan_b3(const float* __restrict__ x, const float* __restrict__ thr,
                          const float* __restrict__ tab, const float* __restrict__ w3,
                          const float* __restrict__ b3,
                          unsigned char* __restrict__ d0, float* __restrict__ base3){
  if (blockIdx.x >= NZQBLK){
    // ---------------- base3 part ----------------
    const int wave = threadIdx.x >> 6, lane = threadIdx.x & 63;
    const int pix = (blockIdx.x - NZQBLK) * 4 + wave;
    if (pix >= P3) return;
    const int oh = pix / H3, ow = pix % H3;
    float acc[3] = {0, 0, 0};
    for (int c = lane; c < C2O; c += 64){
      const float* w = w3 + c * 27;  // [c][o][kh][kw]
#pragma unroll
      for (int kh = 0; kh < 3; ++kh){
        int ih = oh - kh; if (ih < 0 || ih >= H2) continue;
        int prr = pat36(ih) * 5;
#pragma unroll
        for (int kw = 0; kw < 3; ++kw){
          int iw = ow - kw; if (iw < 0 || iw >= H2) continue;
          float a2 = fmaxf(tab[c * 25 + prr + pat36(iw)], 0.f);
#pragma unroll
          for (int o = 0; o < 3; ++o) acc[o] += w[o * 9 + kh * 3 + kw] * a2;
        }
      }
    }
#pragma unroll
    for (int o = 0; o < 3; ++o){
      for (int off = 32; off; off >>= 1) acc[o] += __shfl_down(acc[o], off);
    }
    if (lane == 0){
#pragma unroll
      for (int o = 0; o < 3; ++o) base3[o * P3 + pix] = acc[o] + b3[o];
    }
    return;
  }

  // ---------------- scan part: 64 pixels x 500 channels ----------------
  const int b = blockIdx.x >> 2;
  const int tile = (blockIdx.x & 3) * 64;
  const int t = threadIdx.x;            // 256
  const int q = t & 15, cg = t >> 4;    // pixel-quad, channel-group

  __shared__ unsigned char um[256];

  unsigned m = 0;
  const int pbase = tile + 4 * q;
  for (int c = cg; c < C_; c += 16){
    float tc = thr[c];
    const float4 v = *(const float4*)(x + ((size_t)(b * C_ + c)) * P_ + pbase);
    if (fabsf(v.x) >= tc) m |= 1u;
    if (fabsf(v.y) >= tc) m |= 2u;
    if (fabsf(v.z) >= tc) m |= 4u;
    if (fabsf(v.w) >= tc) m |= 8u;
  }
  um[t] = (unsigned char)m;
  __syncthreads();
  if (t < 64){
    const int qq = t >> 2, j = t & 3;
    unsigned mm = 0;
#pragma unroll
    for (int g = 0; g < 16; ++g) mm |= um[g * 16 + qq];
    d0[b * P_ + tile + t] = (unsigned char)((mm >> j) & 1u);
  }
}

// =====================================================================
// k_final: one block per image (256 threads). Reads the image's 256 d0
// flags; clean -> write relu(base3 crop); dirty -> exact local chain:
// topk/quant -> d1 -> u1 -> d2 -> u2 -> out, block-local (global scratch
// regions are block-private; __syncthreads orders them within the block).
// =====================================================================
__global__ void k_final(const float* __restrict__ x, const float* __restrict__ l1,
                        const float* __restrict__ jumpp, const float* __restrict__ tab,
                        const float* __restrict__ w1, const float* __restrict__ b1,
                        const float* __restrict__ w2, const float* __restrict__ w3,
                        const float* __restrict__ base3, const unsigned char* __restrict__ d0,
                        signed char* __restrict__ zq, float* __restrict__ u1,
                        float* __restrict__ u2, float* __restrict__ out, int have){
  const int b = blockIdx.x;
  const int t = threadIdx.x;          // 256
  const int wave = t >> 6, lane = t & 63;

  __shared__ unsigned char hot[P_];
  __shared__ unsigned char d1s[P1];
  __shared__ unsigned char d2s[P2];
  __shared__ int s_any;
  __shared__ float sx[C_];
  __shared__ unsigned char rm[C_];
  __shared__ unsigned long long red[4];
  __shared__ int sel[KTOP];

  hot[t] = d0[b * P_ + t];
  if (t == 0) s_any = 0;
  __syncthreads();
  if (hot[t]) s_any = 1;              // benign race
  __syncthreads();

  if (!s_any){
    // -------- clean path: out = relu(base3 crop), float4 stores --------
    for (int i = t; i < 3 * OW_ * (OW_ / 4); i += 256){   // 768
      int o = i >> 8, rr = i & 255;
      int r = rr >> 3, q4 = rr & 7;
      int oh = r + CROP, ow0 = q4 * 4 + CROP;
      const float* bp = base3 + o * P3 + oh * H3 + ow0;
      float4 res;
      res.x = fmaxf(bp[0], 0.f);
      res.y = fmaxf(bp[1], 0.f);
      res.z = fmaxf(bp[2], 0.f);
      res.w = fmaxf(bp[3], 0.f);
      *(float4*)(out + ((size_t)(b * 3 + o) * OW_ + r) * OW_ + q4 * 4) = res;
    }
    return;
  }
  if (!have) return;   // workspace too small for dirty path (never for bench)

  const float J = jumpp[0];

  // -------- stage A: exact top-30 + quant codes for each hot pixel --------
  for (int px = 0; px < P_; ++px){
    if (!hot[px]) continue;
    for (int c = t; c < C_; c += 256){ sx[c] = x[(b * C_ + c) * P_ + px]; rm[c] = 0; }
    __syncthreads();
    for (int it = 0; it < KTOP; ++it){
      unsigned long long best = 0ULL;
      for (int c = t; c < C_; c += 256){
        if (!rm[c]){
          unsigned long long key =
            ((unsigned long long)__float_as_uint(fabsf(sx[c])) << 32) |
            (unsigned int)(C_ - 1 - c);          // ties -> lower index wins
          if (key > best) best = key;
        }
      }
      for (int off = 32; off; off >>= 1){
        unsigned long long o2 = __shfl_down(best, off);
        if (o2 > best) best = o2;
      }
      if ((t & 63) == 0) red[t >> 6] = best;
      __syncthreads();
      if (t == 0){
        unsigned long long mx = red[0];
        for (int wv = 1; wv < 4; ++wv) if (red[wv] > mx) mx = red[wv];
        int idx = C_ - 1 - (int)(mx & 0xffffffffULL);
        sel[it] = idx;
        rm[idx] = 1;
      }
      __syncthreads();
    }
    for (int c = t; c < C_; c += 256) zq[(b * C_ + c) * P_ + px] = 0;
    __syncthreads();
    if (t < KTOP){
      int c = sel[t];
      float r = sx[c] / l1[c];
      float qv = 0.5f * (sgnf(r - J) + sgnf(r + J));  // {-1,-0.5,0,0.5,1}
      int code = (int)(2.f * qv);                     // {-2,-1,0,1,2}
      if (code) zq[(b * C_ + c) * P_ + px] = (signed char)code;
    }
    __syncthreads();
  }

  // -------- stage B: d1 flags --------
  for (int p1 = t; p1 < P1; p1 += 256){
    int ih = p1 / H1, iw = p1 - (p1 / H1) * H1;
    int h0 = max(0, (ih - 2) >> 1), h1v = min(H_ - 1, ih >> 1);
    int w0 = max(0, (iw - 2) >> 1), w1v = min(H_ - 1, iw >> 1);
    int any = 0;
    for (int h = h0; h <= h1v; ++h)
      for (int w = w0; w <= w1v; ++w)
        any |= hot[h * H_ + w];
    d1s[p1] = (unsigned char)(any != 0);
  }
  __syncthreads();

  // -------- stage D: d2 flags --------
  for (int p2 = t; p2 < P2; p2 += 256){
    int oh = p2 / H2, ow = p2 - (p2 / H2) * H2;
    int any = 0;
    for (int kh = 0; kh < 3; ++kh){
      int ih = oh - kh; if (ih < 0 || ih >= H1) continue;
      for (int kw = 0; kw < 3; ++kw){
        int iw = ow - kw; if (iw < 0 || iw >= H1) continue;
        any |= d1s[ih * H1 + iw];
      }
    }
    d2s[p2] = (unsigned char)(any != 0);
  }
  __syncthreads();

  // -------- stage C: u1 at dirty-1 pixels (waves split pixels) --------
  for (int p1 = wave; p1 < P1; p1 += 4){
    if (!d1s[p1]) continue;
    int ih = p1 / H1, iw = p1 - (p1 / H1) * H1;
    float acc[5] = {0,0,0,0,0};
    int h0 = max(0, (ih - 2) >> 1), h1v = min(H_ - 1, ih >> 1);
    int w0 = max(0, (iw - 2) >> 1), w1v = min(H_ - 1, iw >> 1);
    for (int h = h0; h <= h1v; ++h)
      for (int w = w0; w <= w1v; ++w){
        if (!hot[h * H_ + w]) continue;
        int kh = ih - 2 * h, kw = iw - 2 * w;
        const signed char* zp = zq + (size_t)(b * C_) * P_ + h * H_ + w;
        for (int c = 0; c < C_; ++c){
          int code = zp[(size_t)c * P_];
          if (!code) continue;
          float val = 0.5f * (float)code * l1[c];
          const float* wp = w1 + (size_t)(c * C1O) * 16 + kh * 4 + kw;
#pragma unroll
          for (int j = 0; j < 5; ++j){
            int c1 = j * 64 + lane;
            if (c1 < C1O) acc[j] += wp[(size_t)c1 * 16] * val;
          }
        }
      }
#pragma unroll
    for (int j = 0; j < 5; ++j){
      int c1 = j * 64 + lane;
      if (c1 < C1O){
        float bb = b1[c1];
        u1[(size_t)(b * C1O + c1) * P1 + p1] = fmaxf(bb + acc[j], 0.f) - fmaxf(bb, 0.f);
      }
    }
  }
  __syncthreads();

  // -------- stage E: u2 at dirty-2 pixels --------
  for (int p2 = wave; p2 < P2; p2 += 4){
    if (!d2s[p2]) continue;
    int oh = p2 / H2, ow = p2 - (p2 / H2) * H2;
    float acc[2] = {0,0};
    for (int kh = 0; kh < 3; ++kh){
      int ih = oh - kh; if (ih < 0 || ih >= H1) continue;
      for (int kw = 0; kw < 3; ++kw){
        int iw = ow - kw; if (iw < 0 || iw >= H1) continue;
        if (!d1s[ih * H1 + iw]) continue;
        const float* up = u1 + (size_t)(b * C1O) * P1 + ih * H1 + iw;
        const float* wb = w2 + kh * 3 + kw;
        for (int c1 = 0; c1 < C1O; ++c1){
          float uv = up[(size_t)c1 * P1];
          if (uv == 0.f) continue;
          const float* wp = wb + (size_t)(c1 * C2O) * 9;
#pragma unroll
          for (int j = 0; j < 2; ++j){
            int c2 = j * 64 + lane;
            if (c2 < C2O) acc[j] += wp[(size_t)c2 * 9] * uv;
          }
        }
      }
    }
    int pr = pat36(oh) * 5 + pat36(ow);
#pragma unroll
    for (int j = 0; j < 2; ++j){
      int c2 = j * 64 + lane;
      if (c2 < C2O){
        float bs = tab[c2 * 25 + pr];
        u2[(size_t)(b * C2O + c2) * P2 + p2] = fmaxf(bs + acc[j], 0.f) - fmaxf(bs, 0.f);
      }
    }
  }
  __syncthreads();

  // -------- stage F: output --------
  for (int i = t; i < 3 * OW_ * OW_; i += 256){     // 3072
    int o = i >> 10, rc = i & 1023;
    int r = rc >> 5, cc = rc & 31;
    int oh = r + CROP, ow = cc + CROP;
    float acc = base3[o * P3 + oh * H3 + ow];
    for (int kh = 0; kh < 3; ++kh){
      int ih = oh - kh;
      for (int kw = 0; kw < 3; ++kw){
        int iw = ow - kw;
        if (!d2s[ih * H2 + iw]) continue;
        const float* up = u2 + (size_t)(b * C2O) * P2 + ih * H2 + iw;
        const float* wp = w3 + o * 9 + kh * 3 + kw;
        for (int c2 = 0; c2 < C2O; ++c2){
          float uv = up[(size_t)c2 * P2];
          if (uv != 0.f) acc += wp[c2 * 27] * uv;
        }
      }
    }
    out[((size_t)(b * 3 + o) * OW_ + r) * OW_ + cc] = fmaxf(acc, 0.f);
  }
}

extern "C" void kernel_launch(void* const* d_in, const int* in_sizes, int n_in,
                              void* d_out, int out_size, void* d_ws, size_t ws_size,
                              hipStream_t stream){
  const float* x   = (const float*)d_in[0];
  const float* phi = (const float*)d_in[1];
  const float* jmp = (const float*)d_in[2];
  const float* w1  = (const float*)d_in[3];
  const float* b1  = (const float*)d_in[4];
  const float* w2  = (const float*)d_in[5];
  const float* b2  = (const float*)d_in[6];
  const float* w3  = (const float*)d_in[7];
  const float* b3  = (const float*)d_in[8];
  float* out = (float*)d_out;
  char* ws = (char*)d_ws;

  // workspace layout (bytes, 16B-aligned)
  constexpr size_t OFF_L1  = 0;                                  // 500 f32
  constexpr size_t OFF_THR = OFF_L1  + 2048;
  constexpr size_t OFF_TAB = OFF_THR + 2048;                     // 2500 f32
  constexpr size_t OFF_B3  = OFF_TAB + 10240;                    // 4332 f32
  constexpr size_t OFF_D0  = OFF_B3  + 17344;                    // 32768 u8
  constexpr size_t OFF_ZQ  = OFF_D0  + (size_t)B_ * P_;          // i8 codes
  constexpr size_t OFF_U1  = OFF_ZQ  + (size_t)B_ * C_ * P_;
  constexpr size_t OFF_U2  = OFF_U1  + (size_t)B_ * C1O * P1 * 4;
  constexpr size_t TOTAL   = OFF_U2  + (size_t)B_ * C2O * P2 * 4;

  float* l1p  = (float*)(ws + OFF_L1);
  float* thrp = (float*)(ws + OFF_THR);
  float* tabp = (float*)(ws + OFF_TAB);
  float* b3p  = (float*)(ws + OFF_B3);
  unsigned char* d0p = (unsigned char*)(ws + OFF_D0);
  signed char* zqp = (signed char*)(ws + OFF_ZQ);
  float* u1p = (float*)(ws + OFF_U1);
  float* u2p = (float*)(ws + OFF_U2);
  int have = (ws_size >= TOTAL) ? 1 : 0;

  k_setup  <<<NL1B + 100, 256, 0, stream>>>(phi, jmp, w2, b1, b2, l1p, thrp, tabp);
  k_scan_b3<<<NZQBLK + NB3BLK, 256, 0, stream>>>(x, thrp, tabp, w3, b3, d0p, b3p);
  k_final  <<<B_, 256, 0, stream>>>(x, l1p, jmp, tabp, w1, b1, w2, w3,
                                    b3p, d0p, zqp, u1p, u2p, out, have);
}